// Round 11
// baseline (370.015 us; speedup 1.0000x reference)
//
#include <hip/hip_runtime.h>
#include <math.h>

// LinearAttention (2nd-order derivative-expanded DeltaNet-like), fp32.
// B=2,H=16,S=2048,D=64; n=2; CHUNK=64 real tokens -> 128 virtual rows/chunk.
// la_gram:    per-chunk packed Gram G (65x65 lower-tri) -> d_ws[64MB..72.8MB].
// la_phase1g: R2-structure WY solve, G from global; LDS 46.7K -> 3 blocks/CU.
// la_phase1f: fallback (R2-exact, Gram in LDS) if ws_size too small.
// la_phase2:  cooperative d-sliced scan; NP=3, 32 blocks/pair, 4 blocks/CU.

namespace {
constexpr int PAIRS = 32;   // B*H
constexpr int SLEN  = 2048;
constexpr int D     = 64;
constexpr int CK    = 64;   // real tokens per chunk
constexpr int CN    = 128;  // virtual rows per chunk
constexpr int NCH   = 32;   // chunks
constexpr int NB2   = 32;   // blocks per pair in phase 2
constexpr int NP    = 3;    // positions per phase-2 block (2 outputs + c=63 replica)
constexpr size_t YWORDS = (size_t)PAIRS * NCH * CN * CN;   // 16M floats = 64MB
constexpr int GP = 2145;    // packed 65x65 lower-tri floats per chunk

// _stab: nan->0, clip to +-1e4. Clip is load-bearing (values genuinely overflow);
// NaN check must be explicit (med3/min/max drop NaN to a bound).
__device__ __forceinline__ float stab1(float x) {
    float y = __builtin_amdgcn_fmed3f(x, -10000.f, 10000.f);
    return (x != x) ? 0.f : y;
}

// swizzled float-index into kst: row a, float4 index f4 (0..15), stride 68 floats.
__device__ __forceinline__ int kidx(int a, int f4) {
    return a * 68 + 4 * (f4 ^ ((a >> 2) & 3));
}
} // namespace

// ---------------- la_gram: packed per-chunk Gram -> global ----------------
// grid = PAIRS*NCH (1024), 256 thr. G[a][b] = dot(k[baseT-1+a], k[baseT-1+b]).
__global__ __launch_bounds__(256, 2)
void la_gram(const float* __restrict__ kg, float* __restrict__ gG)
{
    __shared__ float kstf[65 * 68];
    const int blk = blockIdx.x;
    const int p = blk >> 5, nc = blk & 31;
    const int tid = threadIdx.x;
    const int baseT = nc * CK;
    const float* kp = kg + (size_t)p * SLEN * D;

    for (int u = tid; u < 65 * 16; u += 256) {
        int a = u >> 4, f4 = u & 15;
        int src = baseT - 1 + a;
        float4 val = float4{0.f, 0.f, 0.f, 0.f};
        if (src >= 0) val = ((const float4*)(kp + (size_t)src * D))[f4];
        *(float4*)&kstf[kidx(a, f4)] = val;
    }
    __syncthreads();

    float* gps = gG + (size_t)blk * GP;
    for (int tt = tid; tt < 17 * 17; tt += 256) {
        int ta = tt / 17, tb = tt % 17;
        if (tb > ta) continue;
        int a0 = ta * 4, b0 = tb * 4;
        float acc[4][4] = {};
        for (int d4 = 0; d4 < 16; ++d4) {
            float4 av[4], bv[4];
            #pragma unroll
            for (int r = 0; r < 4; ++r) {
                av[r] = *(const float4*)&kstf[kidx(min(a0 + r, 64), d4)];
                bv[r] = *(const float4*)&kstf[kidx(min(b0 + r, 64), d4)];
            }
            #pragma unroll
            for (int r = 0; r < 4; ++r)
                #pragma unroll
                for (int c = 0; c < 4; ++c)
                    acc[r][c] += av[r].x * bv[c].x + av[r].y * bv[c].y
                               + av[r].z * bv[c].z + av[r].w * bv[c].w;
        }
        #pragma unroll
        for (int r = 0; r < 4; ++r)
            #pragma unroll
            for (int c = 0; c < 4; ++c) {
                int a = a0 + r, b = b0 + c;
                if (a <= 64 && b <= a)
                    gps[a * (a + 1) / 2 + b] = acc[r][c];
            }
    }
}

// ---------------- la_phase1g: WY solve, Gram from global ----------------
// grid = PAIRS*NCH*2 (2048): block owns 64 of 128 Y cols, 256 thr (4 waves).
// LDS: Ysh 32K + scm 8K + redsh 6.3K + beta 0.5K = 46.7K -> 3 blocks/CU.
// per g: phase A: all waves partials for g (j === m mod 4) -> redsh. B.
//        phase B: wave0 reduce+solve(g); waves1-3 build strip(g+1) from gG. B.
__global__ __launch_bounds__(256, 3)
void la_phase1g(const float* __restrict__ kg, const float* __restrict__ vg,
                const float* __restrict__ bg, float* __restrict__ ws,
                const float* __restrict__ gG)
{
    __shared__ float Ysh[CN][64];
    __shared__ float scm[2][CN][8];
    __shared__ float redsh[24][66];
    __shared__ float bq4[CK], bh[CK];

    const int blk  = blockIdx.x;
    const int p    = blk >> 6;
    const int nc   = (blk >> 1) & 31;
    const int half = blk & 1;
    const int tid  = threadIdx.x;
    const int col  = tid & 63;
    const int m    = tid >> 6;
    const int baseT = nc * CK;
    const float* kp = kg + (size_t)p * SLEN * D;
    const float* vp = vg + (size_t)p * SLEN * D;
    const float* bp = bg + (size_t)p * SLEN;
    const float* gps = gG + (size_t)(p * NCH + nc) * GP;

    if (tid < CK) {
        float bv = bp[baseT + tid];
        bq4[tid] = 0.25f * bv;
        bh[tid]  = 0.5f  * bv;
    }
    __syncthreads();

    // ---- Y init (rows i=2c+s). half0: coef*beta*k[t-s], half1: coef*beta*v[t-s].
    const float* srcBase = half ? vp : kp;
    for (int u = tid; u < CN * 16; u += 256) {
        int i = u >> 4, f4 = u & 15;
        int ci = i >> 1, si = i & 1;
        float sc = si ? bh[ci] : -bh[ci];
        int srcT = baseT + ci - si;
        float4 val = float4{0.f, 0.f, 0.f, 0.f};
        if (srcT >= 0) val = ((const float4*)(srcBase + (size_t)srcT * D))[f4];
        val.x *= sc; val.y *= sc; val.z *= sc; val.w *= sc;
        *(float4*)&Ysh[i][f4 * 4] = val;
    }
    // ---- strip(0) -> scm[0]. A[i][j] = sgn*0.25*beta[t_i]*G[ai][aj];
    // a=(i>>1)-(i&1)+1; sgn=+1 iff (i^j) even; packed G via (amax,amin).
    for (int e = tid; e < 64; e += 256) {
        int j = e >> 3, r = e & 7;
        int ai = (r >> 1) - (r & 1) + 1;
        int aj = (j >> 1) - (j & 1) + 1;
        int amax = max(ai, aj), amin = min(ai, aj);
        float sgn = ((r ^ j) & 1) ? -1.f : 1.f;
        scm[0][j][r] = sgn * bq4[r >> 1] * gps[amax * (amax + 1) / 2 + amin];
    }
    __syncthreads();

    for (int g = 0; g < 16; ++g) {
        const int buf = g & 1;
        // ---- phase A: partials for g, wave m handles j === m (mod 4)
        float acc[8] = {};
        for (int j = m; j < 8 * g; j += 4) {
            float yv = Ysh[j][col];
            const float4 a03 = *(const float4*)&scm[buf][j][0];
            const float4 a47 = *(const float4*)&scm[buf][j][4];
            acc[0] += a03.x * yv; acc[1] += a03.y * yv;
            acc[2] += a03.z * yv; acc[3] += a03.w * yv;
            acc[4] += a47.x * yv; acc[5] += a47.y * yv;
            acc[6] += a47.z * yv; acc[7] += a47.w * yv;
        }
        if (m > 0) {
            #pragma unroll
            for (int r = 0; r < 8; ++r) redsh[(m - 1) * 8 + r][col] = acc[r];
        }
        __syncthreads();
        // ---- phase B: wave0 reduce+solve; waves1-3 build strip(g+1) from gG
        if (m == 0) {
            if (g > 0) {
                #pragma unroll
                for (int r = 0; r < 8; ++r)
                    acc[r] += redsh[r][col] + redsh[8 + r][col] + redsh[16 + r][col];
            }
            float yn[8];
            #pragma unroll
            for (int r = 0; r < 8; ++r) {
                float val = Ysh[8 * g + r][col] - acc[r];
                #pragma unroll
                for (int rp = 0; rp < 8; ++rp)
                    if (rp < r) val -= scm[buf][8 * g + rp][r] * yn[rp];
                yn[r] = val;
                Ysh[8 * g + r][col] = val;
            }
        } else if (g < 15) {
            const int T = g + 1, bufB = T & 1;
            const int nel = 8 * (8 * T + 8);
            for (int e = tid - 64; e < nel; e += 192) {
                int j = e >> 3, r = e & 7;
                int i = 8 * T + r;
                int ai = (i >> 1) - (i & 1) + 1;
                int aj = (j >> 1) - (j & 1) + 1;
                int amax = max(ai, aj), amin = min(ai, aj);
                float sgn = ((i ^ j) & 1) ? -1.f : 1.f;
                scm[bufB][j][r] = sgn * bq4[i >> 1] * gps[amax * (amax + 1) / 2 + amin];
            }
        }
        __syncthreads();
    }

    // ---- writeback this half's 64 columns
    float* gY = ws + (size_t)(p * NCH + nc) * (CN * CN) + half * 64;
    for (int u = tid; u < CN * 16; u += 256) {
        int r = u >> 4, f4 = u & 15;
        *(float4*)&gY[r * CN + f4 * 4] = *(const float4*)&Ysh[r][f4 * 4];
    }
}

// ---------------- la_phase1f: fallback (R2-exact, Gram in LDS) ----------------
__global__ __launch_bounds__(256, 2)
void la_phase1f(const float* __restrict__ kg, const float* __restrict__ vg,
                const float* __restrict__ bg, float* __restrict__ ws)
{
    __shared__ float Ysh[CN][64];
    __shared__ float Gm[65][66];
    __shared__ char  ureg[17680];
    __shared__ float bq4[CK], bh[CK];

    float* kstf = (float*)ureg;
    float* scm  = (float*)ureg;                         // [2][128][8] = 8192 B
    float (*redsh)[66] = (float(*)[66])(ureg + 8192);   // [24][66]

    const int blk  = blockIdx.x;
    const int p    = blk >> 6;
    const int nc   = (blk >> 1) & 31;
    const int half = blk & 1;
    const int tid  = threadIdx.x;
    const int baseT = nc * CK;
    const float* kp = kg + (size_t)p * SLEN * D;
    const float* vp = vg + (size_t)p * SLEN * D;
    const float* bp = bg + (size_t)p * SLEN;

    for (int u = tid; u < 65 * 16; u += 256) {
        int a = u >> 4, f4 = u & 15;
        int src = baseT - 1 + a;
        float4 val = float4{0.f, 0.f, 0.f, 0.f};
        if (src >= 0) val = ((const float4*)(kp + (size_t)src * D))[f4];
        *(float4*)&kstf[kidx(a, f4)] = val;
    }
    if (tid < CK) {
        float bv = bp[baseT + tid];
        bq4[tid] = 0.25f * bv;
        bh[tid]  = 0.5f  * bv;
    }
    __syncthreads();

    for (int u = tid; u < CN * 16; u += 256) {
        int i = u >> 4, f4 = u & 15;
        int ci = i >> 1, si = i & 1;
        float sc = si ? bh[ci] : -bh[ci];
        float4 val = float4{0.f, 0.f, 0.f, 0.f};
        if (half == 0) {
            val = *(const float4*)&kstf[kidx(ci - si + 1, f4)];
        } else {
            int srcT = baseT + ci - si;
            if (srcT >= 0) val = ((const float4*)(vp + (size_t)srcT * D))[f4];
        }
        val.x *= sc; val.y *= sc; val.z *= sc; val.w *= sc;
        *(float4*)&Ysh[i][f4 * 4] = val;
    }

    for (int tt = tid; tt < 17 * 17; tt += 256) {
        int ta = tt / 17, tb = tt % 17;
        if (tb > ta) continue;
        int a0 = ta * 4, b0 = tb * 4;
        float acc[4][4] = {};
        for (int d4 = 0; d4 < 16; ++d4) {
            float4 av[4], bv[4];
            #pragma unroll
            for (int r = 0; r < 4; ++r) {
                av[r] = *(const float4*)&kstf[kidx(min(a0 + r, 64), d4)];
                bv[r] = *(const float4*)&kstf[kidx(min(b0 + r, 64), d4)];
            }
            #pragma unroll
            for (int r = 0; r < 4; ++r)
                #pragma unroll
                for (int c = 0; c < 4; ++c)
                    acc[r][c] += av[r].x * bv[c].x + av[r].y * bv[c].y
                               + av[r].z * bv[c].z + av[r].w * bv[c].w;
        }
        #pragma unroll
        for (int r = 0; r < 4; ++r)
            #pragma unroll
            for (int c = 0; c < 4; ++c)
                if (a0 + r <= 64 && b0 + c <= 64) {
                    Gm[a0 + r][b0 + c] = acc[r][c];
                    Gm[b0 + c][a0 + r] = acc[r][c];
                }
    }
    __syncthreads();

    auto stripf = [&](int g, int t0, int tstride) {
        int buf = g & 1;
        int jmax = 8 * g + 8;
        for (int e = t0; e < 8 * jmax; e += tstride) {
            int j = e >> 3, r = e & 7;
            int i = 8 * g + r;
            int ai = (i >> 1) - (i & 1) + 1;
            int aj = (j >> 1) - (j & 1) + 1;
            float sgn = ((i ^ j) & 1) ? -1.f : 1.f;
            scm[(buf * CN + j) * 8 + r] = sgn * bq4[i >> 1] * Gm[ai][aj];
        }
    };

    stripf(0, tid, 256);
    __syncthreads();

    const int col = tid & 63;
    const int m   = tid >> 6;
    for (int g = 0; g < 16; ++g) {
        const int buf = g & 1;
        float acc[8] = {};
        for (int j = m; j < 8 * g; j += 4) {
            float yv = Ysh[j][col];
            const float4 a03 = *(const float4*)&scm[(buf * CN + j) * 8];
            const float4 a47 = *(const float4*)&scm[(buf * CN + j) * 8 + 4];
            acc[0] += a03.x * yv; acc[1] += a03.y * yv;
            acc[2] += a03.z * yv; acc[3] += a03.w * yv;
            acc[4] += a47.x * yv; acc[5] += a47.y * yv;
            acc[6] += a47.z * yv; acc[7] += a47.w * yv;
        }
        if (m > 0) {
            #pragma unroll
            for (int r = 0; r < 8; ++r) redsh[(m - 1) * 8 + r][col] = acc[r];
        }
        __syncthreads();
        if (m == 0) {
            if (g > 0) {
                #pragma unroll
                for (int r = 0; r < 8; ++r)
                    acc[r] += redsh[r][col] + redsh[8 + r][col] + redsh[16 + r][col];
            }
            float yn[8];
            #pragma unroll
            for (int r = 0; r < 8; ++r) {
                float val = Ysh[8 * g + r][col] - acc[r];
                #pragma unroll
                for (int rp = 0; rp < 8; ++rp)
                    if (rp < r) val -= scm[(buf * CN + 8 * g + rp) * 8 + r] * yn[rp];
                yn[r] = val;
                Ysh[8 * g + r][col] = val;
            }
        } else if (g < 15) {
            stripf(g + 1, tid - 64, 192);
        }
        __syncthreads();
    }

    float* gY = ws + (size_t)(p * NCH + nc) * (CN * CN) + half * 64;
    for (int u = tid; u < CN * 16; u += 256) {
        int r = u >> 4, f4 = u & 15;
        *(float4*)&gY[r * CN + f4 * 4] = *(const float4*)&Ysh[r][f4 * 4];
    }
}

// ---------------- Phase 2: cooperative d-sliced chunk scan ----------------
// grid = PAIRS*NB2 (1024 -> 4 blocks/CU, full occupancy), block = 512 (8 waves).
// Wave w does d-slice [8w,8w+8) partials (col e=lane); h in LDS hsh[64][65].
// NP=3: P=0,1 -> c = nb*2+P (outputs), P=2 -> c=63 (replica, always).
// Schedule: R1 -> B1 -> UV0 -> B2 -> R2 + stage_write -> B3 -> out/UV1 -> B4 ->
//           row-mapped h-update -> B5. pKO aliases pR1 (disjoint live ranges).
__global__ __launch_bounds__(512, 8)
void la_phase2(const float* __restrict__ qg, const float* __restrict__ ws,
               float* __restrict__ outg)
{
    __shared__ float  WU[2][NP][256];   // staged [w0|u0|w1|u1] per position, dbuf
    __shared__ float  Qs[2][NP][64];    // staged raw q rows (0.5 scale at output)
    __shared__ char   puni[sizeof(float2) * 8 * NP * 64];  // pR1 | pKO union
    __shared__ float  UV0[NP][64];
    __shared__ float  UV1r[64];
    __shared__ float  hsh[64][65];      // 65 === 1 mod 32: both access modes free

    float*  pR1 = (float*)puni;          // [8][NP][64] kh0 partials
    float2* pKO = (float2*)puni;         // [8][NP][64] {kh1, oac} partials

    const int blk  = blockIdx.x;
    const int p    = blk >> 5, nb = blk & 31;
    const int tid  = threadIdx.x;
    const int w    = tid >> 6, lane = tid & 63;
    const int hd   = tid >> 3;
    const int he0  = (tid & 7) * 8;

    const float* qp = qg + (size_t)p * SLEN * D;
    float* op = outg + (size_t)p * SLEN * D;
    const float* wsbase = ws + (size_t)p * NCH * (CN * CN);

    const int cMain = nb * 2 + w;      // valid for w<2 (output positions)

    float4 wuR = float4{0.f, 0.f, 0.f, 0.f};
    float  qR  = 0.f;

    auto stage_load = [&](int nc) {
        const float* gY = wsbase + (size_t)nc * (CN * CN);
        if (w < 2) {
            wuR = *(const float4*)(gY + (size_t)(2 * cMain) * CN + lane * 4);
            int t = nc * CK + cMain;
            qR = qp[(size_t)((t > 0) ? t - 1 : 0) * D + lane];
        } else if (w == 2) {
            wuR = *(const float4*)(gY + (size_t)126 * CN + lane * 4);
            qR = qp[(size_t)(nc * CK + 62) * D + lane];
        }
    };
    auto stage_write = [&](int buf) {
        if (w < NP) {
            *(float4*)&WU[buf][w][lane * 4] = wuR;
            Qs[buf][w][lane] = qR;
        }
    };

    for (int idx = tid; idx < 64 * 65; idx += 512) (&hsh[0][0])[idx] = 0.f;
    stage_load(0);
    stage_write(0);
    __syncthreads();

    for (int nc = 0; nc < NCH; ++nc) {
        const int buf = nc & 1;

        float hs[8];
        #pragma unroll
        for (int j = 0; j < 8; ++j) hs[j] = hsh[8 * w + j][lane];

        if (nc + 1 < NCH) stage_load(nc + 1);   // issue early; LDS-write before B3

        // ---- ROUND 1: kh0 partials over d-slice [8w,8w+8)
        #pragma unroll
        for (int P = 0; P < NP; ++P) {
            float4 a = *(const float4*)&WU[buf][P][8 * w];
            float4 b = *(const float4*)&WU[buf][P][8 * w + 4];
            pR1[(w * NP + P) * 64 + lane] =
                  ((a.x * hs[0] + a.y * hs[1]) + (a.z * hs[2] + a.w * hs[3]))
                + ((b.x * hs[4] + b.y * hs[5]) + (b.z * hs[6] + b.w * hs[7]));
        }
        __syncthreads();   // B1

        // ---- UV0 designated: wave w (< NP) reduces position P=w
        if (w < NP) {
            float s = 0.f;
            #pragma unroll
            for (int wv = 0; wv < 8; ++wv) s += pR1[(wv * NP + w) * 64 + lane];
            UV0[w][lane] = WU[buf][w][64 + lane] - s;
        }
        __syncthreads();   // B2

        // ---- ROUND 2: st1 = stab(h + w0*uv0); packed {kh1, oac} partials
        #pragma unroll
        for (int P = 0; P < NP; ++P) {
            float uv0 = UV0[P][lane];
            float4 w0a = *(const float4*)&WU[buf][P][8 * w];
            float4 w0b = *(const float4*)&WU[buf][P][8 * w + 4];
            float4 w1a = *(const float4*)&WU[buf][P][128 + 8 * w];
            float4 w1b = *(const float4*)&WU[buf][P][128 + 8 * w + 4];
            float4 qa  = *(const float4*)&Qs[buf][P][8 * w];
            float4 qb  = *(const float4*)&Qs[buf][P][8 * w + 4];
            float st0 = stab1(hs[0] + w0a.x * uv0);
            float st1 = stab1(hs[1] + w0a.y * uv0);
            float st2 = stab1(hs[2] + w0a.z * uv0);
            float st3 = stab1(hs[3] + w0a.w * uv0);
            float st4 = stab1(hs[4] + w0b.x * uv0);
            float st5 = stab1(hs[5] + w0b.y * uv0);
            float st6 = stab1(hs[6] + w0b.z * uv0);
            float st7 = stab1(hs[7] + w0b.w * uv0);
            float kh = ((w1a.x * st0 + w1a.y * st1) + (w1a.z * st2 + w1a.w * st3))
                     + ((w1b.x * st4 + w1b.y * st5) + (w1b.z * st6 + w1b.w * st7));
            float oa = ((qa.x * st0 + qa.y * st1) + (qa.z * st2 + qa.w * st3))
                     + ((qb.x * st4 + qb.y * st5) + (qb.z * st6 + qb.w * st7));
            pKO[(w * NP + P) * 64 + lane] = float2{kh, oa};
        }
        stage_write(buf ^ 1);
        __syncthreads();   // B3

        // ---- designated: outputs (waves 0,1) and UV1r (wave 2)
        if (w < 2) {
            float skh = 0.f, soa = 0.f;
            #pragma unroll
            for (int wv = 0; wv < 8; ++wv) {
                float2 t = pKO[(wv * NP + w) * 64 + lane];
                skh += t.x; soa += t.y;
            }
            float uv1 = WU[buf][w][192 + lane] - skh;
            int t = nc * CK + cMain;
            float outv = 0.5f * (Qs[buf][w][lane] * uv1 + soa);
            op[(size_t)t * D + lane] = (t > 0) ? outv : 0.f;
        } else if (w == 2) {
            float skh = 0.f;
            #pragma unroll
            for (int wv = 0; wv < 8; ++wv) skh += pKO[(wv * NP + 2) * 64 + lane].x;
            UV1r[lane] = WU[buf][2][192 + lane] - skh;
        }
        __syncthreads();   // B4

        // ---- H-UPDATE, row-mapped: thread = (row hd, cols he0..he0+7).
        // state2 = stab(stab(h + w0_63 x uv0_63) + w1_63 x uv1_63);
        // h' = 0.25*x*y*(1+tanh(z)), y = 2x/(rownorm+1e-6); 3-shfl norm reduce.
        {
            float w0d = WU[buf][2][hd];
            float w1d = WU[buf][2][128 + hd];
            float st2v[8];
            float ssum = 0.f;
            #pragma unroll
            for (int j = 0; j < 8; ++j) {
                float st1 = stab1(hsh[hd][he0 + j] + w0d * UV0[2][he0 + j]);
                float st2 = stab1(st1 + w1d * UV1r[he0 + j]);
                st2v[j] = st2;
                ssum += st2 * st2;
            }
            ssum += __shfl_xor(ssum, 1);
            ssum += __shfl_xor(ssum, 2);
            ssum += __shfl_xor(ssum, 4);
            float xn = __builtin_amdgcn_sqrtf(ssum) + 1e-6f;
            float s2 = 2.f * __builtin_amdgcn_rcpf(xn);
            #pragma unroll
            for (int j = 0; j < 8; ++j) {
                float x  = st2v[j];
                float y  = x * s2;                       // in [-2, 2]
                float y2 = y * y;
                float e  = __builtin_amdgcn_exp2f(y * (2.3022078f + 0.1029432f * y2));
                float th = (e - 1.f) * __builtin_amdgcn_rcpf(e + 1.f);
                hsh[hd][he0 + j] = 0.25f * x * y * (1.f + th);
            }
        }
        __syncthreads();   // B5 (h visible to next chunk's column loads)
    }
}

extern "C" void kernel_launch(void* const* d_in, const int* in_sizes, int n_in,
                              void* d_out, int out_size, void* d_ws, size_t ws_size,
                              hipStream_t stream)
{
    (void)in_sizes; (void)n_in; (void)out_size;
    const float* q    = (const float*)d_in[0];
    const float* k    = (const float*)d_in[1];
    const float* v    = (const float*)d_in[2];
    const float* beta = (const float*)d_in[3];
    float* ws  = (float*)d_ws;
    float* out = (float*)d_out;

    const size_t need = (YWORDS + (size_t)PAIRS * NCH * GP) * sizeof(float); // ~72.8MB
    if (ws_size >= need) {
        float* gG = ws + YWORDS;
        la_gram<<<PAIRS * NCH, 256, 0, stream>>>(k, gG);
        la_phase1g<<<PAIRS * NCH * 2, 256, 0, stream>>>(k, v, beta, ws, gG);
    } else {
        la_phase1f<<<PAIRS * NCH * 2, 256, 0, stream>>>(k, v, beta, ws);
    }
    la_phase2<<<PAIRS * NB2, 512, 0, stream>>>(q, ws, out);
}

// Round 12
// 260.853 us; speedup vs baseline: 1.4185x; 1.4185x over previous
//
#include <hip/hip_runtime.h>
#include <math.h>

// LinearAttention (2nd-order derivative-expanded DeltaNet-like), fp32.
// B=2,H=16,S=2048,D=64; n=2; CHUNK=64 real tokens -> 128 virtual rows/chunk.
// la_gram:    per-chunk packed Gram G (65x65 lower-tri) -> d_ws[64MB..72.8MB].
// la_phase1g: R2-structure WY solve, G from global; LDS 46.7K -> 3 blocks/CU.
// la_phase1f: fallback (Gram in LDS) if ws_size too small.
// la_phase2:  R6-config cooperative d-sliced scan; NP=5, 16 blocks/pair, 2/CU.

namespace {
constexpr int PAIRS = 32;   // B*H
constexpr int SLEN  = 2048;
constexpr int D     = 64;
constexpr int CK    = 64;   // real tokens per chunk
constexpr int CN    = 128;  // virtual rows per chunk
constexpr int NCH   = 32;   // chunks
constexpr int NB2   = 16;   // blocks per pair in phase 2
constexpr int NP    = 5;    // positions per phase-2 block (4 outputs + c=63 replica)
constexpr size_t YWORDS = (size_t)PAIRS * NCH * CN * CN;   // 16M floats = 64MB
constexpr int GP = 2145;    // packed 65x65 lower-tri floats per chunk

// _stab: nan->0, clip to +-1e4. Clip is load-bearing (values genuinely overflow);
// NaN check must be explicit (med3/min/max drop NaN to a bound).
__device__ __forceinline__ float stab1(float x) {
    float y = __builtin_amdgcn_fmed3f(x, -10000.f, 10000.f);
    return (x != x) ? 0.f : y;
}

// swizzled float-index into kst: row a, float4 index f4 (0..15), stride 68 floats.
__device__ __forceinline__ int kidx(int a, int f4) {
    return a * 68 + 4 * (f4 ^ ((a >> 2) & 3));
}
} // namespace

// ---------------- la_gram: packed per-chunk Gram -> global ----------------
// grid = PAIRS*NCH (1024), 256 thr. G[a][b] = dot(k[baseT-1+a], k[baseT-1+b]).
__global__ __launch_bounds__(256, 2)
void la_gram(const float* __restrict__ kg, float* __restrict__ gG)
{
    __shared__ float kstf[65 * 68];
    const int blk = blockIdx.x;
    const int p = blk >> 5, nc = blk & 31;
    const int tid = threadIdx.x;
    const int baseT = nc * CK;
    const float* kp = kg + (size_t)p * SLEN * D;

    for (int u = tid; u < 65 * 16; u += 256) {
        int a = u >> 4, f4 = u & 15;
        int src = baseT - 1 + a;
        float4 val = float4{0.f, 0.f, 0.f, 0.f};
        if (src >= 0) val = ((const float4*)(kp + (size_t)src * D))[f4];
        *(float4*)&kstf[kidx(a, f4)] = val;
    }
    __syncthreads();

    float* gps = gG + (size_t)blk * GP;
    for (int tt = tid; tt < 17 * 17; tt += 256) {
        int ta = tt / 17, tb = tt % 17;
        if (tb > ta) continue;
        int a0 = ta * 4, b0 = tb * 4;
        float acc[4][4] = {};
        for (int d4 = 0; d4 < 16; ++d4) {
            float4 av[4], bv[4];
            #pragma unroll
            for (int r = 0; r < 4; ++r) {
                av[r] = *(const float4*)&kstf[kidx(min(a0 + r, 64), d4)];
                bv[r] = *(const float4*)&kstf[kidx(min(b0 + r, 64), d4)];
            }
            #pragma unroll
            for (int r = 0; r < 4; ++r)
                #pragma unroll
                for (int c = 0; c < 4; ++c)
                    acc[r][c] += av[r].x * bv[c].x + av[r].y * bv[c].y
                               + av[r].z * bv[c].z + av[r].w * bv[c].w;
        }
        #pragma unroll
        for (int r = 0; r < 4; ++r)
            #pragma unroll
            for (int c = 0; c < 4; ++c) {
                int a = a0 + r, b = b0 + c;
                if (a <= 64 && b <= a)
                    gps[a * (a + 1) / 2 + b] = acc[r][c];
            }
    }
}

// ---------------- la_phase1g: WY solve, Gram from global ----------------
// grid = PAIRS*NCH*2 (2048): block owns 64 of 128 Y cols, 256 thr (4 waves).
// LDS: Ysh 32K + scm 8K + redsh 6.3K + beta 0.5K = 46.7K -> 3 blocks/CU.
// per g: phase A: all waves partials for g (j === m mod 4) -> redsh. B.
//        phase B: wave0 reduce+solve(g); waves1-3 build strip(g+1) from gG. B.
__global__ __launch_bounds__(256, 3)
void la_phase1g(const float* __restrict__ kg, const float* __restrict__ vg,
                const float* __restrict__ bg, float* __restrict__ ws,
                const float* __restrict__ gG)
{
    __shared__ float Ysh[CN][64];
    __shared__ float scm[2][CN][8];
    __shared__ float redsh[24][66];
    __shared__ float bq4[CK], bh[CK];

    const int blk  = blockIdx.x;
    const int p    = blk >> 6;
    const int nc   = (blk >> 1) & 31;
    const int half = blk & 1;
    const int tid  = threadIdx.x;
    const int col  = tid & 63;
    const int m    = tid >> 6;
    const int baseT = nc * CK;
    const float* kp = kg + (size_t)p * SLEN * D;
    const float* vp = vg + (size_t)p * SLEN * D;
    const float* bp = bg + (size_t)p * SLEN;
    const float* gps = gG + (size_t)(p * NCH + nc) * GP;

    if (tid < CK) {
        float bv = bp[baseT + tid];
        bq4[tid] = 0.25f * bv;
        bh[tid]  = 0.5f  * bv;
    }
    __syncthreads();

    // ---- Y init (rows i=2c+s). half0: coef*beta*k[t-s], half1: coef*beta*v[t-s].
    const float* srcBase = half ? vp : kp;
    for (int u = tid; u < CN * 16; u += 256) {
        int i = u >> 4, f4 = u & 15;
        int ci = i >> 1, si = i & 1;
        float sc = si ? bh[ci] : -bh[ci];
        int srcT = baseT + ci - si;
        float4 val = float4{0.f, 0.f, 0.f, 0.f};
        if (srcT >= 0) val = ((const float4*)(srcBase + (size_t)srcT * D))[f4];
        val.x *= sc; val.y *= sc; val.z *= sc; val.w *= sc;
        *(float4*)&Ysh[i][f4 * 4] = val;
    }
    // ---- strip(0) -> scm[0]. A[i][j] = sgn*0.25*beta[t_i]*G[ai][aj];
    // a=(i>>1)-(i&1)+1; sgn=+1 iff (i^j) even; packed G via (amax,amin).
    for (int e = tid; e < 64; e += 256) {
        int j = e >> 3, r = e & 7;
        int ai = (r >> 1) - (r & 1) + 1;
        int aj = (j >> 1) - (j & 1) + 1;
        int amax = max(ai, aj), amin = min(ai, aj);
        float sgn = ((r ^ j) & 1) ? -1.f : 1.f;
        scm[0][j][r] = sgn * bq4[r >> 1] * gps[amax * (amax + 1) / 2 + amin];
    }
    __syncthreads();

    for (int g = 0; g < 16; ++g) {
        const int buf = g & 1;
        // ---- phase A: partials for g, wave m handles j === m (mod 4)
        float acc[8] = {};
        for (int j = m; j < 8 * g; j += 4) {
            float yv = Ysh[j][col];
            const float4 a03 = *(const float4*)&scm[buf][j][0];
            const float4 a47 = *(const float4*)&scm[buf][j][4];
            acc[0] += a03.x * yv; acc[1] += a03.y * yv;
            acc[2] += a03.z * yv; acc[3] += a03.w * yv;
            acc[4] += a47.x * yv; acc[5] += a47.y * yv;
            acc[6] += a47.z * yv; acc[7] += a47.w * yv;
        }
        if (m > 0) {
            #pragma unroll
            for (int r = 0; r < 8; ++r) redsh[(m - 1) * 8 + r][col] = acc[r];
        }
        __syncthreads();
        // ---- phase B: wave0 reduce+solve; waves1-3 build strip(g+1) from gG
        if (m == 0) {
            if (g > 0) {
                #pragma unroll
                for (int r = 0; r < 8; ++r)
                    acc[r] += redsh[r][col] + redsh[8 + r][col] + redsh[16 + r][col];
            }
            float yn[8];
            #pragma unroll
            for (int r = 0; r < 8; ++r) {
                float val = Ysh[8 * g + r][col] - acc[r];
                #pragma unroll
                for (int rp = 0; rp < 8; ++rp)
                    if (rp < r) val -= scm[buf][8 * g + rp][r] * yn[rp];
                yn[r] = val;
                Ysh[8 * g + r][col] = val;
            }
        } else if (g < 15) {
            const int T = g + 1, bufB = T & 1;
            const int nel = 8 * (8 * T + 8);
            for (int e = tid - 64; e < nel; e += 192) {
                int j = e >> 3, r = e & 7;
                int i = 8 * T + r;
                int ai = (i >> 1) - (i & 1) + 1;
                int aj = (j >> 1) - (j & 1) + 1;
                int amax = max(ai, aj), amin = min(ai, aj);
                float sgn = ((i ^ j) & 1) ? -1.f : 1.f;
                scm[bufB][j][r] = sgn * bq4[i >> 1] * gps[amax * (amax + 1) / 2 + amin];
            }
        }
        __syncthreads();
    }

    // ---- writeback this half's 64 columns
    float* gY = ws + (size_t)(p * NCH + nc) * (CN * CN) + half * 64;
    for (int u = tid; u < CN * 16; u += 256) {
        int r = u >> 4, f4 = u & 15;
        *(float4*)&gY[r * CN + f4 * 4] = *(const float4*)&Ysh[r][f4 * 4];
    }
}

// ---------------- la_phase1f: fallback (Gram in LDS) ----------------
__global__ __launch_bounds__(256, 2)
void la_phase1f(const float* __restrict__ kg, const float* __restrict__ vg,
                const float* __restrict__ bg, float* __restrict__ ws)
{
    __shared__ float Ysh[CN][64];
    __shared__ float Gm[65][66];
    __shared__ char  ureg[17680];
    __shared__ float bq4[CK], bh[CK];

    float* kstf = (float*)ureg;
    float* scm  = (float*)ureg;                         // [2][128][8] = 8192 B
    float (*redsh)[66] = (float(*)[66])(ureg + 8192);   // [24][66]

    const int blk  = blockIdx.x;
    const int p    = blk >> 6;
    const int nc   = (blk >> 1) & 31;
    const int half = blk & 1;
    const int tid  = threadIdx.x;
    const int baseT = nc * CK;
    const float* kp = kg + (size_t)p * SLEN * D;
    const float* vp = vg + (size_t)p * SLEN * D;
    const float* bp = bg + (size_t)p * SLEN;

    for (int u = tid; u < 65 * 16; u += 256) {
        int a = u >> 4, f4 = u & 15;
        int src = baseT - 1 + a;
        float4 val = float4{0.f, 0.f, 0.f, 0.f};
        if (src >= 0) val = ((const float4*)(kp + (size_t)src * D))[f4];
        *(float4*)&kstf[kidx(a, f4)] = val;
    }
    if (tid < CK) {
        float bv = bp[baseT + tid];
        bq4[tid] = 0.25f * bv;
        bh[tid]  = 0.5f  * bv;
    }
    __syncthreads();

    for (int u = tid; u < CN * 16; u += 256) {
        int i = u >> 4, f4 = u & 15;
        int ci = i >> 1, si = i & 1;
        float sc = si ? bh[ci] : -bh[ci];
        float4 val = float4{0.f, 0.f, 0.f, 0.f};
        if (half == 0) {
            val = *(const float4*)&kstf[kidx(ci - si + 1, f4)];
        } else {
            int srcT = baseT + ci - si;
            if (srcT >= 0) val = ((const float4*)(vp + (size_t)srcT * D))[f4];
        }
        val.x *= sc; val.y *= sc; val.z *= sc; val.w *= sc;
        *(float4*)&Ysh[i][f4 * 4] = val;
    }

    for (int tt = tid; tt < 17 * 17; tt += 256) {
        int ta = tt / 17, tb = tt % 17;
        if (tb > ta) continue;
        int a0 = ta * 4, b0 = tb * 4;
        float acc[4][4] = {};
        for (int d4 = 0; d4 < 16; ++d4) {
            float4 av[4], bv[4];
            #pragma unroll
            for (int r = 0; r < 4; ++r) {
                av[r] = *(const float4*)&kstf[kidx(min(a0 + r, 64), d4)];
                bv[r] = *(const float4*)&kstf[kidx(min(b0 + r, 64), d4)];
            }
            #pragma unroll
            for (int r = 0; r < 4; ++r)
                #pragma unroll
                for (int c = 0; c < 4; ++c)
                    acc[r][c] += av[r].x * bv[c].x + av[r].y * bv[c].y
                               + av[r].z * bv[c].z + av[r].w * bv[c].w;
        }
        #pragma unroll
        for (int r = 0; r < 4; ++r)
            #pragma unroll
            for (int c = 0; c < 4; ++c)
                if (a0 + r <= 64 && b0 + c <= 64) {
                    Gm[a0 + r][b0 + c] = acc[r][c];
                    Gm[b0 + c][a0 + r] = acc[r][c];
                }
    }
    __syncthreads();

    auto stripf = [&](int g, int t0, int tstride) {
        int buf = g & 1;
        int jmax = 8 * g + 8;
        for (int e = t0; e < 8 * jmax; e += tstride) {
            int j = e >> 3, r = e & 7;
            int i = 8 * g + r;
            int ai = (i >> 1) - (i & 1) + 1;
            int aj = (j >> 1) - (j & 1) + 1;
            float sgn = ((i ^ j) & 1) ? -1.f : 1.f;
            scm[(buf * CN + j) * 8 + r] = sgn * bq4[i >> 1] * Gm[ai][aj];
        }
    };

    stripf(0, tid, 256);
    __syncthreads();

    const int col = tid & 63;
    const int m   = tid >> 6;
    for (int g = 0; g < 16; ++g) {
        const int buf = g & 1;
        float acc[8] = {};
        for (int j = m; j < 8 * g; j += 4) {
            float yv = Ysh[j][col];
            const float4 a03 = *(const float4*)&scm[(buf * CN + j) * 8];
            const float4 a47 = *(const float4*)&scm[(buf * CN + j) * 8 + 4];
            acc[0] += a03.x * yv; acc[1] += a03.y * yv;
            acc[2] += a03.z * yv; acc[3] += a03.w * yv;
            acc[4] += a47.x * yv; acc[5] += a47.y * yv;
            acc[6] += a47.z * yv; acc[7] += a47.w * yv;
        }
        if (m > 0) {
            #pragma unroll
            for (int r = 0; r < 8; ++r) redsh[(m - 1) * 8 + r][col] = acc[r];
        }
        __syncthreads();
        if (m == 0) {
            if (g > 0) {
                #pragma unroll
                for (int r = 0; r < 8; ++r)
                    acc[r] += redsh[r][col] + redsh[8 + r][col] + redsh[16 + r][col];
            }
            float yn[8];
            #pragma unroll
            for (int r = 0; r < 8; ++r) {
                float val = Ysh[8 * g + r][col] - acc[r];
                #pragma unroll
                for (int rp = 0; rp < 8; ++rp)
                    if (rp < r) val -= scm[(buf * CN + 8 * g + rp) * 8 + r] * yn[rp];
                yn[r] = val;
                Ysh[8 * g + r][col] = val;
            }
        } else if (g < 15) {
            stripf(g + 1, tid - 64, 192);
        }
        __syncthreads();
    }

    float* gY = ws + (size_t)(p * NCH + nc) * (CN * CN) + half * 64;
    for (int u = tid; u < CN * 16; u += 256) {
        int r = u >> 4, f4 = u & 15;
        *(float4*)&gY[r * CN + f4 * 4] = *(const float4*)&Ysh[r][f4 * 4];
    }
}

// ---------------- Phase 2: cooperative d-sliced chunk scan (R6 config) --------
// grid = PAIRS*NB2 (512 blocks -> 2/CU), block = 512 (8 waves).
// Wave w contributes partials for d-slice [8w,8w+8) (column e=lane); h lives in
// LDS hsh[64][67]. NP=5: P=0..3 -> c = nb*4+P (outputs), P=4 -> c=63.
// Schedule: R1 -> B1 -> UV0 designated -> B2 -> R2 + stage_write -> B3 ->
//           out/UV1 designated -> B4 -> row-mapped h-update -> B5.
__global__ __launch_bounds__(512, 4)
void la_phase2(const float* __restrict__ qg, const float* __restrict__ ws,
               float* __restrict__ outg)
{
    __shared__ float WU[2][NP][256];    // staged [w0|u0|w1|u1] per position, dbuf
    __shared__ float Qs[2][NP][64];     // staged raw q rows (0.5 scale at output)
    __shared__ float pR1[8][NP][64];    // kh0 partials (per d-slice wave)
    __shared__ float pKH[8][NP][64];    // kh1 partials
    __shared__ float pOA[8][NP][64];    // oac partials
    __shared__ float UV0[NP][64];       // uv0 per position
    __shared__ float UV1r[64];          // uv1 at c=63
    __shared__ float hsh[64][67];       // h[d][e]; 67%32=3 -> both modes conflict-free

    const int blk  = blockIdx.x;
    const int p    = blk >> 4, nb = blk & 15;
    const int tid  = threadIdx.x;
    const int w    = tid >> 6, lane = tid & 63;
    const int hd   = tid >> 3;          // h-update: row 0..63
    const int he0  = (tid & 7) * 8;     // h-update: 8 columns [he0, he0+8)

    const float* qp = qg + (size_t)p * SLEN * D;
    float* op = outg + (size_t)p * SLEN * D;
    const float* wsbase = ws + (size_t)p * NCH * (CN * CN);

    const int cMain = nb * 4 + w;      // valid for w<4 (output positions)

    float4 wuR = float4{0.f, 0.f, 0.f, 0.f};
    float  qR  = 0.f;

    auto stage_load = [&](int nc) {
        const float* gY = wsbase + (size_t)nc * (CN * CN);
        if (w < 4) {
            wuR = *(const float4*)(gY + (size_t)(2 * cMain) * CN + lane * 4);
            int t = nc * CK + cMain;
            qR = qp[(size_t)((t > 0) ? t - 1 : 0) * D + lane];
        } else if (w == 4) {
            wuR = *(const float4*)(gY + (size_t)126 * CN + lane * 4);
            qR = qp[(size_t)(nc * CK + 62) * D + lane];
        }
    };
    auto stage_write = [&](int buf) {
        if (w < NP) {
            *(float4*)&WU[buf][w][lane * 4] = wuR;
            Qs[buf][w][lane] = qR;
        }
    };

    for (int idx = tid; idx < 64 * 67; idx += 512) (&hsh[0][0])[idx] = 0.f;
    stage_load(0);
    stage_write(0);
    __syncthreads();

    for (int nc = 0; nc < NCH; ++nc) {
        const int buf = nc & 1;

        // h d-slice for this wave (column e=lane), fresh after previous B5
        float hs[8];
        #pragma unroll
        for (int j = 0; j < 8; ++j) hs[j] = hsh[8 * w + j][lane];

        if (nc + 1 < NCH) stage_load(nc + 1);   // issue early; LDS-write before B3

        // ---- ROUND 1: kh0 partials over d-slice [8w,8w+8)
        #pragma unroll
        for (int P = 0; P < NP; ++P) {
            float4 a = *(const float4*)&WU[buf][P][8 * w];
            float4 b = *(const float4*)&WU[buf][P][8 * w + 4];
            pR1[w][P][lane] =
                  ((a.x * hs[0] + a.y * hs[1]) + (a.z * hs[2] + a.w * hs[3]))
                + ((b.x * hs[4] + b.y * hs[5]) + (b.z * hs[6] + b.w * hs[7]));
        }
        __syncthreads();   // B1

        // ---- UV0 designated: wave w (< NP) reduces position P=w
        if (w < NP) {
            float s = 0.f;
            #pragma unroll
            for (int wv = 0; wv < 8; ++wv) s += pR1[wv][w][lane];
            UV0[w][lane] = WU[buf][w][64 + lane] - s;
        }
        __syncthreads();   // B2

        // ---- ROUND 2: st1 = stab(h + w0*uv0); kh1/oac partials over d-slice
        #pragma unroll
        for (int P = 0; P < NP; ++P) {
            float uv0 = UV0[P][lane];
            float4 w0a = *(const float4*)&WU[buf][P][8 * w];
            float4 w0b = *(const float4*)&WU[buf][P][8 * w + 4];
            float4 w1a = *(const float4*)&WU[buf][P][128 + 8 * w];
            float4 w1b = *(const float4*)&WU[buf][P][128 + 8 * w + 4];
            float4 qa  = *(const float4*)&Qs[buf][P][8 * w];
            float4 qb  = *(const float4*)&Qs[buf][P][8 * w + 4];
            float st0 = stab1(hs[0] + w0a.x * uv0);
            float st1 = stab1(hs[1] + w0a.y * uv0);
            float st2 = stab1(hs[2] + w0a.z * uv0);
            float st3 = stab1(hs[3] + w0a.w * uv0);
            float st4 = stab1(hs[4] + w0b.x * uv0);
            float st5 = stab1(hs[5] + w0b.y * uv0);
            float st6 = stab1(hs[6] + w0b.z * uv0);
            float st7 = stab1(hs[7] + w0b.w * uv0);
            pKH[w][P][lane] =
                  ((w1a.x * st0 + w1a.y * st1) + (w1a.z * st2 + w1a.w * st3))
                + ((w1b.x * st4 + w1b.y * st5) + (w1b.z * st6 + w1b.w * st7));
            pOA[w][P][lane] =
                  ((qa.x * st0 + qa.y * st1) + (qa.z * st2 + qa.w * st3))
                + ((qb.x * st4 + qb.y * st5) + (qb.z * st6 + qb.w * st7));
        }
        stage_write(buf ^ 1);
        __syncthreads();   // B3

        // ---- designated: outputs (waves 0-3) and UV1r (wave 4)
        if (w < 4) {
            float skh = 0.f, soa = 0.f;
            #pragma unroll
            for (int wv = 0; wv < 8; ++wv) {
                skh += pKH[wv][w][lane];
                soa += pOA[wv][w][lane];
            }
            float uv1 = WU[buf][w][192 + lane] - skh;
            int t = nc * CK + cMain;
            float outv = 0.5f * (Qs[buf][w][lane] * uv1 + soa);
            op[(size_t)t * D + lane] = (t > 0) ? outv : 0.f;
        } else if (w == 4) {
            float skh = 0.f;
            #pragma unroll
            for (int wv = 0; wv < 8; ++wv) skh += pKH[wv][4][lane];
            UV1r[lane] = WU[buf][4][192 + lane] - skh;
        }
        __syncthreads();   // B4

        // ---- H-UPDATE, row-mapped: thread = (row hd, cols he0..he0+7).
        // state2 = stab(stab(h + w0_63 x uv0_63) + w1_63 x uv1_63);
        // h' = 0.25*x*y*(1+tanh(z)), y = 2x/(rownorm+1e-6); 3-shfl norm reduce.
        {
            float w0d = WU[buf][4][hd];
            float w1d = WU[buf][4][128 + hd];
            float st2v[8];
            float ssum = 0.f;
            #pragma unroll
            for (int j = 0; j < 8; ++j) {
                float st1 = stab1(hsh[hd][he0 + j] + w0d * UV0[4][he0 + j]);
                float st2 = stab1(st1 + w1d * UV1r[he0 + j]);
                st2v[j] = st2;
                ssum += st2 * st2;
            }
            ssum += __shfl_xor(ssum, 1);
            ssum += __shfl_xor(ssum, 2);
            ssum += __shfl_xor(ssum, 4);
            float xn = __builtin_amdgcn_sqrtf(ssum) + 1e-6f;
            float s2 = 2.f * __builtin_amdgcn_rcpf(xn);
            #pragma unroll
            for (int j = 0; j < 8; ++j) {
                float x  = st2v[j];
                float y  = x * s2;                       // in [-2, 2]
                float y2 = y * y;
                float e  = __builtin_amdgcn_exp2f(y * (2.3022078f + 0.1029432f * y2));
                float th = (e - 1.f) * __builtin_amdgcn_rcpf(e + 1.f);
                hsh[hd][he0 + j] = 0.25f * x * y * (1.f + th);
            }
        }
        __syncthreads();   // B5 (h visible to next chunk's column loads)
    }
}

extern "C" void kernel_launch(void* const* d_in, const int* in_sizes, int n_in,
                              void* d_out, int out_size, void* d_ws, size_t ws_size,
                              hipStream_t stream)
{
    (void)in_sizes; (void)n_in; (void)out_size;
    const float* q    = (const float*)d_in[0];
    const float* k    = (const float*)d_in[1];
    const float* v    = (const float*)d_in[2];
    const float* beta = (const float*)d_in[3];
    float* ws  = (float*)d_ws;
    float* out = (float*)d_out;

    const size_t need = (YWORDS + (size_t)PAIRS * NCH * GP) * sizeof(float); // ~72.8MB
    if (ws_size >= need) {
        float* gG = ws + YWORDS;
        la_gram<<<PAIRS * NCH, 256, 0, stream>>>(k, gG);
        la_phase1g<<<PAIRS * NCH * 2, 256, 0, stream>>>(k, v, beta, ws, gG);
    } else {
        la_phase1f<<<PAIRS * NCH * 2, 256, 0, stream>>>(k, v, beta, ws);
    }
    la_phase2<<<PAIRS * NB2, 512, 0, stream>>>(q, ws, out);
}